// Round 7
// baseline (149.545 us; speedup 1.0000x reference)
//
#include <hip/hip_runtime.h>

typedef __attribute__((ext_vector_type(8))) __bf16  bf16x8;
typedef __attribute__((ext_vector_type(8))) short   short8;
typedef __attribute__((ext_vector_type(4))) float   f32x4;

#define DM   512
#define BM   128
#define BN   128
#define BK   64
#define NNT  4                 // n-tiles (512/128)
#define NKT  8                 // k-tiles (512/64)
#define TILEB (BN*BK*2)        // 16 KiB per B tile image

__device__ __forceinline__ short f2bf(float f) {
  union { float f; unsigned u; } v; v.f = f;
  unsigned r = v.u + 0x7fffu + ((v.u >> 16) & 1u);   // RNE
  return (short)(r >> 16);
}

// XOR swizzle within a [rows][64 bf16] tile (128B row stride).
__device__ __forceinline__ int swz(int r, int cbyte) {
  return (r * 128 + cbyte) ^ ((r & 7) << 4);
}

// Fold softmax(taps) + conv into per-head G[h][e][d], stored as pre-swizzled
// per-(h,nt,kt) 128x64 LDS tile images. 8 d's per thread.
__global__ void build_g_kernel(const float* __restrict__ w,
                               const float* __restrict__ fcw,
                               short* __restrict__ Gt) {
  int idx = blockIdx.x * 256 + threadIdx.x;   // 8*512*512/8 threads
  int h  = idx >> 15;
  int t  = idx & 32767;
  int e  = t >> 6;
  int d0 = (t & 63) << 3;
  float w0 = w[h*3+0], w1 = w[h*3+1], w2 = w[h*3+2];
  float mx = fmaxf(w0, fmaxf(w1, w2));
  float e0 = __expf(w0-mx), e1 = __expf(w1-mx), e2 = __expf(w2-mx);
  float inv = 1.0f / (e0 + e1 + e2);
  float w0n = e0*inv, w1n = e1*inv, w2n = e2*inv;
  const float* row = fcw + e * DM;
  float v[10];
  v[0] = (d0 > 0) ? row[d0-1] : 0.0f;
  float4 a = *(const float4*)(row + d0);
  float4 b = *(const float4*)(row + d0 + 4);
  v[1]=a.x; v[2]=a.y; v[3]=a.z; v[4]=a.w;
  v[5]=b.x; v[6]=b.y; v[7]=b.z; v[8]=b.w;
  v[9] = (d0 + 8 < DM) ? row[d0+8] : 0.0f;
  short8 sv;
  #pragma unroll
  for (int j = 0; j < 8; ++j)
    sv[j] = f2bf(w1n*v[j+1] + w0n*v[j+2] + w2n*v[j]);
  int nt = e >> 7, r = e & 127;
  int kt = d0 >> 6, c = d0 & 63;
  char* tile = (char*)Gt + (size_t)((h * NNT + nt) * NKT + kt) * TILEB;
  *(short8*)(tile + swz(r, c * 2)) = sv;
}

// y[R,e] = sum_d x[R,d] * G[R%8][e,d]; R = h + 8*t
// A: direct global->reg->bf16 fragments (no LDS).  B: gload_lds dbuf.
__global__ __launch_bounds__(256, 3) void gemm_kernel(const float* __restrict__ x,
                                                      const short* __restrict__ Gt,
                                                      float* __restrict__ out) {
  int bid = blockIdx.x;          // 2048 blocks
  int h   = bid & 7;             // head == XCD (round-robin dispatch heuristic)
  int idx = bid >> 3;            // within XCD: nt fastest -> 4 blocks share x-tile
  int nt  = idx & 3;
  int mt  = idx >> 2;
  int tid  = threadIdx.x;
  int lane = tid & 63;
  int wid  = tid >> 6;
  int wr = wid >> 1, wc = wid & 1;   // 2x2 wave grid, 64x64 per wave

  __shared__ short Blds[2][BN * BK];   // 2 x 16 KiB swizzled

  const char* Bsrc0 = (const char*)Gt + (size_t)(h * NNT + nt) * NKT * TILEB;
  // A base for this wave: rows h + 8*(mt*128 + wr*64 + m*16 + (lane&15))
  const float* Arow0 = x + (size_t)(h + 8 * ((size_t)mt * BM + wr * 64 + (lane & 15))) * DM
                         + (lane >> 4) * 8;

  auto stageB = [&](int kt, int buf) {   // 4 x gload_lds dwordx4 per thread
    const char* src = Bsrc0 + kt * TILEB;
    char* dst = (char*)Blds[buf];
    #pragma unroll
    for (int p = 0; p < 4; ++p)
      __builtin_amdgcn_global_load_lds((const void*)(src + p * 4096 + tid * 16),
                                       (void*)(dst + p * 4096 + wid * 1024), 16, 0, 0);
  };

  f32x4 acc[4][4] = {};   // wave tile 64x64

  auto loadAraw = [&](int kt, int ks, float4 (&raw)[8]) {
    const float* base = Arow0 + kt * BK + ks * 32;
    #pragma unroll
    for (int m = 0; m < 4; ++m) {
      const float* p = base + (size_t)(8 * 16 * m) * DM;   // +16 rows => +128*DM floats
      raw[2*m]   = *(const float4*)p;
      raw[2*m+1] = *(const float4*)(p + 4);
    }
  };
  auto cvtA = [&](const float4 (&raw)[8], bf16x8 (&af)[4]) {
    #pragma unroll
    for (int m = 0; m < 4; ++m) {
      bf16x8 v;
      v[0]=(__bf16)raw[2*m].x;   v[1]=(__bf16)raw[2*m].y;
      v[2]=(__bf16)raw[2*m].z;   v[3]=(__bf16)raw[2*m].w;
      v[4]=(__bf16)raw[2*m+1].x; v[5]=(__bf16)raw[2*m+1].y;
      v[6]=(__bf16)raw[2*m+1].z; v[7]=(__bf16)raw[2*m+1].w;
      af[m] = v;
    }
  };
  auto rdB = [&](const char* Bp, int ks, bf16x8 (&bf)[4]) {
    #pragma unroll
    for (int n = 0; n < 4; ++n)
      bf[n] = *(const bf16x8*)(Bp + swz(wc*64 + n*16 + (lane & 15),
                                        ks*64 + (lane >> 4) * 16));
  };
  auto mma16 = [&](const bf16x8 (&af)[4], const bf16x8 (&bf)[4]) {
    #pragma unroll
    for (int m = 0; m < 4; ++m)
      #pragma unroll
      for (int n = 0; n < 4; ++n)
        acc[m][n] = __builtin_amdgcn_mfma_f32_16x16x32_bf16(af[m], bf[n], acc[m][n], 0, 0, 0);
  };

  // prologue
  stageB(0, 0);
  __syncthreads();

  for (int kt = 0; kt < NKT; ++kt) {
    int cur = kt & 1;
    const char* Bp = (const char*)Blds[cur];
    float4 raw[8];
    bf16x8 af[4], bf[4];

    loadAraw(kt, 0, raw);               // ks0 A loads in flight
    if (kt + 1 < NKT) stageB(kt + 1, cur ^ 1);

    cvtA(raw, af);                      // waits ks0 loads
    loadAraw(kt, 1, raw);               // ks1 loads fly under ks0 MFMA
    rdB(Bp, 0, bf);
    mma16(af, bf);

    cvtA(raw, af);                      // waits ks1 loads
    rdB(Bp, 1, bf);
    mma16(af, bf);

    __syncthreads();                    // stageB(kt+1) issued ~full tile ago: free drain
  }

  // epilogue: C/D layout col = lane&15, row = (lane>>4)*4 + j
  int e0 = nt * BN + wc * 64 + (lane & 15);
  #pragma unroll
  for (int m = 0; m < 4; ++m) {
    int tq = mt * BM + wr * 64 + m * 16 + ((lane >> 4) << 2);
    #pragma unroll
    for (int j = 0; j < 4; ++j) {
      int R = h + 8 * (tq + j);
      float* orow = out + (size_t)R * DM + e0;
      #pragma unroll
      for (int n = 0; n < 4; ++n)
        orow[n * 16] = acc[m][n][j];
    }
  }
}

extern "C" void kernel_launch(void* const* d_in, const int* in_sizes, int n_in,
                              void* d_out, int out_size, void* d_ws, size_t ws_size,
                              hipStream_t stream) {
  const float* x   = (const float*)d_in[0];
  const float* w   = (const float*)d_in[1];
  const float* fcw = (const float*)d_in[2];
  float* out = (float*)d_out;
  short* Gt  = (short*)d_ws;   // 8*4*8 tiles * 16 KiB = 4 MiB pre-swizzled

  hipLaunchKernelGGL(build_g_kernel, dim3((8 * DM * DM / 8) / 256), dim3(256), 0, stream,
                     w, fcw, Gt);
  hipLaunchKernelGGL(gemm_kernel, dim3(8 * 64 * NNT), dim3(256), 0, stream,
                     x, Gt, out);
}

// Round 8
// 97.581 us; speedup vs baseline: 1.5325x; 1.5325x over previous
//
#include <hip/hip_runtime.h>

typedef __attribute__((ext_vector_type(8))) __bf16  bf16x8;
typedef __attribute__((ext_vector_type(8))) short   short8;
typedef __attribute__((ext_vector_type(4))) float   f32x4;

#define DM   512
#define BM   256
#define BN   256
#define BK   64
#define NNT  2                 // n-tiles (512/256)
#define NKT  8                 // k-tiles (512/64)
#define TILEB 32768            // bytes per B tile image (256x64 bf16)

__device__ __forceinline__ short f2bf(float f) {
  union { float f; unsigned u; } v; v.f = f;
  unsigned r = v.u + 0x7fffu + ((v.u >> 16) & 1u);   // RNE
  return (short)(r >> 16);
}

// XOR swizzle within a [rows][64 bf16] tile (128B row stride).
__device__ __forceinline__ int swz(int r, int cbyte) {
  return (r * 128 + cbyte) ^ ((r & 7) << 4);
}

// Fold softmax(taps) + conv into per-head G[h][e][d], stored as pre-swizzled
// per-(h,nt,kt) 256x64 LDS tile images. 8 d's per thread.
__global__ void build_g_kernel(const float* __restrict__ w,
                               const float* __restrict__ fcw,
                               short* __restrict__ Gt) {
  int idx = blockIdx.x * 256 + threadIdx.x;   // 8*512*512/8 threads
  int h  = idx >> 15;
  int t  = idx & 32767;
  int e  = t >> 6;
  int d0 = (t & 63) << 3;
  float w0 = w[h*3+0], w1 = w[h*3+1], w2 = w[h*3+2];
  float mx = fmaxf(w0, fmaxf(w1, w2));
  float e0 = __expf(w0-mx), e1 = __expf(w1-mx), e2 = __expf(w2-mx);
  float inv = 1.0f / (e0 + e1 + e2);
  float w0n = e0*inv, w1n = e1*inv, w2n = e2*inv;
  const float* row = fcw + e * DM;
  float v[10];
  v[0] = (d0 > 0) ? row[d0-1] : 0.0f;
  float4 a = *(const float4*)(row + d0);
  float4 b = *(const float4*)(row + d0 + 4);
  v[1]=a.x; v[2]=a.y; v[3]=a.z; v[4]=a.w;
  v[5]=b.x; v[6]=b.y; v[7]=b.z; v[8]=b.w;
  v[9] = (d0 + 8 < DM) ? row[d0+8] : 0.0f;
  short8 sv;
  #pragma unroll
  for (int j = 0; j < 8; ++j)
    sv[j] = f2bf(w1n*v[j+1] + w0n*v[j+2] + w2n*v[j]);
  int nt = e >> 8, r = e & 255;
  int kt = d0 >> 6, c = d0 & 63;
  char* tile = (char*)Gt + (size_t)((h * NNT + nt) * NKT + kt) * TILEB;
  *(short8*)(tile + swz(r, c * 2)) = sv;
}

// y[R,e] = sum_d x[R,d] * G[R%8][e,d]; R = h + 8*t
// Persistent: one block per (h,mt), both nt reps in sequence (A reused,
// rep0's C-stores drain under rep1's k-loop).
__global__ __launch_bounds__(512, 2) void gemm_kernel(const float* __restrict__ x,
                                                      const short* __restrict__ Gt,
                                                      float* __restrict__ out) {
  int bid = blockIdx.x;          // 256 blocks = 1/CU
  int h   = bid & 7;             // head == XCD
  int mt  = bid >> 3;            // 32 mtiles
  int tid  = threadIdx.x;
  int lane = tid & 63;
  int wid  = tid >> 6;
  int wr = wid >> 2, wc = wid & 3;   // 2x4 wave grid, 128x64 per wave

  __shared__ short Alds[2][BM * BK];   // 2 x 32 KiB swizzled
  __shared__ short Blds[2][BN * BK];   // 2 x 32 KiB swizzled

  const char* BsrcH = (const char*)Gt + (size_t)(h * NNT) * NKT * TILEB;
  const float* Abase = x + (size_t)(h + 8 * (size_t)mt * BM) * DM;

  float4 ap[8];   // A prefetch regs

  auto loadA = [&](int kt) {
    #pragma unroll
    for (int p = 0; p < 4; ++p) {
      int r = (tid >> 3) + 64 * p;
      const float* xr = Abase + (size_t)r * 8 * DM + kt * BK + (tid & 7) * 8;
      ap[2*p]   = *(const float4*)xr;
      ap[2*p+1] = *(const float4*)(xr + 4);
    }
  };
  auto stageB = [&](int rep, int kt, int buf) {
    const char* src = BsrcH + (size_t)rep * NKT * TILEB + kt * TILEB;
    char* dst = (char*)Blds[buf];
    #pragma unroll
    for (int p = 0; p < 4; ++p)
      __builtin_amdgcn_global_load_lds((const void*)(src + p * 8192 + tid * 16),
                                       (void*)(dst + p * 8192 + wid * 1024), 16, 0, 0);
  };
  auto writeA = [&](int buf) {
    char* dst = (char*)Alds[buf];
    #pragma unroll
    for (int p = 0; p < 4; ++p) {
      int r = (tid >> 3) + 64 * p;
      short8 sv;
      sv[0]=f2bf(ap[2*p].x);   sv[1]=f2bf(ap[2*p].y);
      sv[2]=f2bf(ap[2*p].z);   sv[3]=f2bf(ap[2*p].w);
      sv[4]=f2bf(ap[2*p+1].x); sv[5]=f2bf(ap[2*p+1].y);
      sv[6]=f2bf(ap[2*p+1].z); sv[7]=f2bf(ap[2*p+1].w);
      *(short8*)(dst + swz(r, (tid & 7) * 16)) = sv;
    }
  };

  f32x4 acc[8][4];
  #pragma unroll
  for (int m = 0; m < 8; ++m)
    #pragma unroll
    for (int n = 0; n < 4; ++n) acc[m][n] = (f32x4){0.f, 0.f, 0.f, 0.f};

  auto computeTile = [&](int cur) {
    const char* Ap = (const char*)Alds[cur];
    const char* Bp = (const char*)Blds[cur];
    #pragma unroll
    for (int ks = 0; ks < 2; ++ks) {
      bf16x8 af[8], bfr[4];
      #pragma unroll
      for (int m = 0; m < 8; ++m)
        af[m] = *(const bf16x8*)(Ap + swz(wr*128 + m*16 + (lane & 15),
                                          ks*64 + (lane >> 4) * 16));
      #pragma unroll
      for (int n = 0; n < 4; ++n)
        bfr[n] = *(const bf16x8*)(Bp + swz(wc*64 + n*16 + (lane & 15),
                                           ks*64 + (lane >> 4) * 16));
      #pragma unroll
      for (int m = 0; m < 8; ++m)
        #pragma unroll
        for (int n = 0; n < 4; ++n)
          acc[m][n] = __builtin_amdgcn_mfma_f32_16x16x32_bf16(af[m], bfr[n], acc[m][n], 0, 0, 0);
    }
  };

  auto prologue = [&](int rep) {   // stage tile 0 of this rep into buf 0
    loadA(0);
    stageB(rep, 0, 0);
    writeA(0);              // waits ap loads (L2-warm on rep1)
    __syncthreads();
  };
  auto kloop = [&](int rep) {
    for (int kt = 0; kt < NKT; ++kt) {
      int cur = kt & 1, nxt = cur ^ 1;
      if (kt + 1 < NKT) {            // issue next tile's loads before compute
        loadA(kt + 1);
        stageB(rep, kt + 1, nxt);
      }
      computeTile(cur);
      if (kt + 1 < NKT) writeA(nxt); // convert + ds_write after compute
      __syncthreads();               // boundary drain
    }
  };
  auto storeC = [&](int rep) {       // C/D layout: col = lane&15, row = (lane>>4)*4+j
    int e0 = rep * BN + wc * 64 + (lane & 15);
    #pragma unroll
    for (int m = 0; m < 8; ++m) {
      int tq = mt * BM + wr * 128 + m * 16 + ((lane >> 4) << 2);
      #pragma unroll
      for (int j = 0; j < 4; ++j) {
        int R = h + 8 * (tq + j);
        float* orow = out + (size_t)R * DM + e0;
        #pragma unroll
        for (int n = 0; n < 4; ++n)
          orow[n * 16] = acc[m][n][j];
      }
    }
  };

  prologue(0);
  kloop(0);
  prologue(1);      // rep1 staging issued BEFORE rep0's stores
  storeC(0);        // stores drain under rep1's entire k-loop
  #pragma unroll
  for (int m = 0; m < 8; ++m)
    #pragma unroll
    for (int n = 0; n < 4; ++n) acc[m][n] = (f32x4){0.f, 0.f, 0.f, 0.f};
  kloop(1);
  storeC(1);
}

extern "C" void kernel_launch(void* const* d_in, const int* in_sizes, int n_in,
                              void* d_out, int out_size, void* d_ws, size_t ws_size,
                              hipStream_t stream) {
  const float* x   = (const float*)d_in[0];
  const float* w   = (const float*)d_in[1];
  const float* fcw = (const float*)d_in[2];
  float* out = (float*)d_out;
  short* Gt  = (short*)d_ws;   // 4 MiB pre-swizzled tile images

  hipLaunchKernelGGL(build_g_kernel, dim3((8 * DM * DM / 8) / 256), dim3(256), 0, stream,
                     w, fcw, Gt);
  hipLaunchKernelGGL(gemm_kernel, dim3(8 * 32), dim3(512), 0, stream,
                     x, Gt, out);
}

// Round 9
// 78.841 us; speedup vs baseline: 1.8968x; 1.2377x over previous
//
#include <hip/hip_runtime.h>

typedef __attribute__((ext_vector_type(8))) __bf16  bf16x8;
typedef __attribute__((ext_vector_type(8))) short   short8;
typedef __attribute__((ext_vector_type(4))) float   f32x4;

#define DM   512
#define BM   128
#define BN   128
#define BK   32
#define NNT  4                 // n-tiles (512/128)
#define NKT  16                // k-tiles (512/32)
#define TILEB (BN*BK*2)        // 8 KiB per B tile image

__device__ __forceinline__ short f2bf(float f) {
  union { float f; unsigned u; } v; v.f = f;
  unsigned r = v.u + 0x7fffu + ((v.u >> 16) & 1u);   // RNE
  return (short)(r >> 16);
}

// XOR swizzle within a [rows][32 bf16] tile (64B row stride), 16B granular.
__device__ __forceinline__ int swz(int r, int cbyte) {
  return (r * 64 + cbyte) ^ ((r & 3) << 4);
}

// Fold softmax(taps) + conv into per-head G[h][e][d], stored as pre-swizzled
// per-(h,nt,kt) 128x32 LDS tile images. 8 d's per thread.
__global__ void build_g_kernel(const float* __restrict__ w,
                               const float* __restrict__ fcw,
                               short* __restrict__ Gt) {
  int idx = blockIdx.x * 256 + threadIdx.x;   // 8*512*512/8 threads
  int h  = idx >> 15;
  int t  = idx & 32767;
  int e  = t >> 6;
  int d0 = (t & 63) << 3;
  float w0 = w[h*3+0], w1 = w[h*3+1], w2 = w[h*3+2];
  float mx = fmaxf(w0, fmaxf(w1, w2));
  float e0 = __expf(w0-mx), e1 = __expf(w1-mx), e2 = __expf(w2-mx);
  float inv = 1.0f / (e0 + e1 + e2);
  float w0n = e0*inv, w1n = e1*inv, w2n = e2*inv;
  const float* row = fcw + e * DM;
  float v[10];
  v[0] = (d0 > 0) ? row[d0-1] : 0.0f;
  float4 a = *(const float4*)(row + d0);
  float4 b = *(const float4*)(row + d0 + 4);
  v[1]=a.x; v[2]=a.y; v[3]=a.z; v[4]=a.w;
  v[5]=b.x; v[6]=b.y; v[7]=b.z; v[8]=b.w;
  v[9] = (d0 + 8 < DM) ? row[d0+8] : 0.0f;
  short8 sv;
  #pragma unroll
  for (int j = 0; j < 8; ++j)
    sv[j] = f2bf(w1n*v[j+1] + w0n*v[j+2] + w2n*v[j]);
  int nt = e >> 7, r = e & 127;
  int kt = d0 >> 5, c = d0 & 31;
  char* tile = (char*)Gt + (size_t)((h * NNT + nt) * NKT + kt) * TILEB;
  *(short8*)(tile + swz(r, c * 2)) = sv;
}

// y[R,e] = sum_d x[R,d] * G[R%8][e,d]; R = h + 8*t
// Small blocks (32 KiB LDS, ~124 VGPR) -> 4 independent blocks/CU.
__global__ __launch_bounds__(256, 4) void gemm_kernel(const float* __restrict__ x,
                                                      const short* __restrict__ Gt,
                                                      float* __restrict__ out) {
  int bid = blockIdx.x;          // 2048 blocks = 8/CU
  int h   = bid & 7;             // head == XCD
  int idx = bid >> 3;
  int nt  = idx & 3;             // nt fastest: co-scheduled nt-quads share A in L2
  int mt  = idx >> 2;            // 64 mtiles
  int tid  = threadIdx.x;
  int lane = tid & 63;
  int wid  = tid >> 6;
  int wr = wid >> 1, wc = wid & 1;   // 2x2 wave grid, 64x64 per wave

  __shared__ short Alds[2][BM * BK];   // 2 x 8 KiB swizzled
  __shared__ short Blds[2][BN * BK];   // 2 x 8 KiB swizzled

  const char* Bsrc0 = (const char*)Gt + (size_t)(h * NNT + nt) * NKT * TILEB;
  const float* Abase = x + (size_t)(h + 8 * (size_t)mt * BM) * DM;

  float4 ap[4];   // A prefetch regs (16 VGPR)

  auto loadA = [&](int kt) {
    #pragma unroll
    for (int p = 0; p < 2; ++p) {
      int r = (tid >> 2) + 64 * p;
      const float* xr = Abase + (size_t)r * 8 * DM + kt * BK + (tid & 3) * 8;
      ap[2*p]   = *(const float4*)xr;
      ap[2*p+1] = *(const float4*)(xr + 4);
    }
  };
  auto stageB = [&](int kt, int buf) {   // 2 x gload_lds dwordx4 per thread
    const char* src = Bsrc0 + kt * TILEB;
    char* dst = (char*)Blds[buf];
    #pragma unroll
    for (int p = 0; p < 2; ++p)
      __builtin_amdgcn_global_load_lds((const void*)(src + p * 4096 + tid * 16),
                                       (void*)(dst + p * 4096 + wid * 1024), 16, 0, 0);
  };
  auto writeA = [&](int buf) {
    char* dst = (char*)Alds[buf];
    #pragma unroll
    for (int p = 0; p < 2; ++p) {
      int r = (tid >> 2) + 64 * p;
      short8 sv;
      sv[0]=f2bf(ap[2*p].x);   sv[1]=f2bf(ap[2*p].y);
      sv[2]=f2bf(ap[2*p].z);   sv[3]=f2bf(ap[2*p].w);
      sv[4]=f2bf(ap[2*p+1].x); sv[5]=f2bf(ap[2*p+1].y);
      sv[6]=f2bf(ap[2*p+1].z); sv[7]=f2bf(ap[2*p+1].w);
      *(short8*)(dst + swz(r, (tid & 3) * 16)) = sv;
    }
  };

  f32x4 acc[4][4] = {};   // wave tile 64x64

  auto computeTile = [&](int cur) {
    const char* Ap = (const char*)Alds[cur];
    const char* Bp = (const char*)Blds[cur];
    bf16x8 af[4], bfr[4];
    #pragma unroll
    for (int m = 0; m < 4; ++m)
      af[m] = *(const bf16x8*)(Ap + swz(wr*64 + m*16 + (lane & 15),
                                        (lane >> 4) * 16));
    #pragma unroll
    for (int n = 0; n < 4; ++n)
      bfr[n] = *(const bf16x8*)(Bp + swz(wc*64 + n*16 + (lane & 15),
                                         (lane >> 4) * 16));
    #pragma unroll
    for (int m = 0; m < 4; ++m)
      #pragma unroll
      for (int n = 0; n < 4; ++n)
        acc[m][n] = __builtin_amdgcn_mfma_f32_16x16x32_bf16(af[m], bfr[n], acc[m][n], 0, 0, 0);
  };

  // prologue: tile 0 -> buf 0
  loadA(0);
  stageB(0, 0);
  writeA(0);
  __syncthreads();

  for (int kt = 0; kt < NKT; ++kt) {
    int cur = kt & 1, nxt = cur ^ 1;
    if (kt + 1 < NKT) {            // issue next tile's loads before compute
      loadA(kt + 1);
      stageB(kt + 1, nxt);
    }
    computeTile(cur);
    if (kt + 1 < NKT) writeA(nxt); // convert + ds_write after compute
    __syncthreads();               // boundary drain
  }

  // epilogue: C/D layout col = lane&15, row = (lane>>4)*4 + j
  int e0 = nt * BN + wc * 64 + (lane & 15);
  #pragma unroll
  for (int m = 0; m < 4; ++m) {
    int tq = mt * BM + wr * 64 + m * 16 + ((lane >> 4) << 2);
    #pragma unroll
    for (int j = 0; j < 4; ++j) {
      int R = h + 8 * (tq + j);
      float* orow = out + (size_t)R * DM + e0;
      #pragma unroll
      for (int n = 0; n < 4; ++n)
        orow[n * 16] = acc[m][n][j];
    }
  }
}

extern "C" void kernel_launch(void* const* d_in, const int* in_sizes, int n_in,
                              void* d_out, int out_size, void* d_ws, size_t ws_size,
                              hipStream_t stream) {
  const float* x   = (const float*)d_in[0];
  const float* w   = (const float*)d_in[1];
  const float* fcw = (const float*)d_in[2];
  float* out = (float*)d_out;
  short* Gt  = (short*)d_ws;   // 8*4*16 tiles * 8 KiB = 4 MiB pre-swizzled

  hipLaunchKernelGGL(build_g_kernel, dim3((8 * DM * DM / 8) / 256), dim3(256), 0, stream,
                     w, fcw, Gt);
  hipLaunchKernelGGL(gemm_kernel, dim3(8 * 64 * NNT), dim3(256), 0, stream,
                     x, Gt, out);
}